// Round 7
// baseline (395.237 us; speedup 1.0000x reference)
//
#include <hip/hip_runtime.h>
#include <hip/hip_bf16.h>
#include <stdint.h>

#define DFEAT 256
#define NPTS  8192

typedef __attribute__((ext_vector_type(8)))  short bf16x8;   // 8 bf16 = 4 VGPRs
typedef __attribute__((ext_vector_type(16))) float f32x16;   // 32x32 C/D
typedef __attribute__((ext_vector_type(4)))  int   int4v;
typedef __attribute__((ext_vector_type(4)))  float f32x4;

__device__ inline uint16_t f2bf(float f) {  // RNE fp32->bf16
  union { float f; uint32_t u; } v; v.f = f;
  return (uint16_t)((v.u + 0x7FFFu + ((v.u >> 16) & 1u)) >> 16);
}

// lgkmcnt(0)-only barrier (no vmcnt drain): all K-loop global loads are
// per-wave register loads, so barriers only need LDS-op visibility.
__device__ inline void barrier_lgkm_only() {
  __asm__ __volatile__("" ::: "memory");
  __builtin_amdgcn_s_waitcnt(0xC07F);   // vmcnt=63, expcnt=7, lgkmcnt=0
  __builtin_amdgcn_s_barrier();
  __asm__ __volatile__("" ::: "memory");
}

// ---------------------------------------------------------------------------
// ws fragment layouts (written by ms_combine):
//  xaf: per 32-point block nb, chunk s=2*ks+g, lane 0..31:
//       X[d = s*8 .. +8][pt = nb*32+lane]  (A/B-frag order, k=d)  (4 MB)
//  xbf: per 32-d block db, chunk u (n/8), lane:
//       X[d = db*32+lane][n = u*8 .. +8]   (PV A-frag order, k=n) (4 MB)
// Every hot-loop wave load is 1KB contiguous.
// ---------------------------------------------------------------------------

// Software-pipelined fused step. Between consecutive barriers, a wave runs
// PV(t) (4 independent accO chains) interleaved with S(t+1) (serial chain),
// then exp/pack(t+1) into the other Ps buffer. ONE lgkm barrier per iter.
__global__ __launch_bounds__(256, 2) void ms_fused(
    const uint16_t* __restrict__ xaf,
    const uint16_t* __restrict__ xbf,
    float* __restrict__ num,           // [256][8192] fp32, zeroed by combine
    float* __restrict__ cs)            // [8192] fp32, zeroed by combine
{
  // Ps[buf][m][n-pair]: dword m*33 + n/2 (odd stride -> conflict-free)
  __shared__ uint32_t Ps[2][64 * 33];

  const int tid  = threadIdx.x;
  const int w    = tid >> 6;
  const int lane = tid & 63;
  const int l31  = lane & 31;
  const int g    = lane >> 5;
  const int bid  = blockIdx.x;
  const int xcd  = bid & 7;                  // blockIdx%8 ~ XCD (heuristic)
  const int q    = xcd >> 1;                 // n-split shared per XCD (L2-hot)
  const int mt   = (bid >> 3) + ((xcd & 1) << 6);
  const int m0   = mt * 64;
  const int a_sub = w >> 1;                  // S n-sub (0/1)
  const int b_sub = w & 1;                   // S m-sub (0/1)

  const char* xafc = (const char*)xaf;
  const char* xbfc = (const char*)xbf;

  // Xm B-fragments resident, one-time coalesced load
  bf16x8 Bm[16];
  {
    const char* bp = xafc + (size_t)(m0 / 32 + b_sub) * 16384 + g * 512 + l31 * 16;
    #pragma unroll
    for (int ks = 0; ks < 16; ++ks)
      Bm[ks] = __builtin_bit_cast(bf16x8, *(const int4v*)(bp + ks * 1024));
  }

  f32x16 accO[2][2];
  #pragma unroll
  for (int i = 0; i < 2; ++i)
    #pragma unroll
    for (int j = 0; j < 2; ++j)
      #pragma unroll
      for (int r = 0; r < 16; ++r) accO[i][j][r] = 0.0f;
  float csacc = 0.0f;

  const int mloc = 32 * b_sub + l31;
  const int j0   = q * 32;

  const char* apb = xafc + (size_t)a_sub * 16384 + g * 512 + l31 * 16;
  const char* xpb = xbfc + g * 512 + l31 * 16;

  bf16x8 Xf[2][4];

  // ---- prologue: S(0) -> exp -> Ps[0]; Xf(0) in flight ----
  {
    const char* ap = apb + (size_t)(j0 * 2) * 16384;
    bf16x8 Af[16];
    #pragma unroll
    for (int ks = 0; ks < 16; ++ks)
      Af[ks] = __builtin_bit_cast(bf16x8, *(const int4v*)(ap + ks * 1024));
    f32x16 s;
    #pragma unroll
    for (int r = 0; r < 16; ++r) s[r] = 0.0f;
    #pragma unroll
    for (int ks = 0; ks < 16; ++ks)
      s = __builtin_amdgcn_mfma_f32_32x32x16_bf16(Af[ks], Bm[ks], s, 0, 0, 0);
    #pragma unroll
    for (int t2 = 0; t2 < 2; ++t2) {
      const char* xp = xpb + (size_t)(2 * w + t2) * 524288 + (size_t)(j0 * 8) * 512;
      #pragma unroll
      for (int ks = 0; ks < 4; ++ks)
        Xf[t2][ks] = __builtin_bit_cast(bf16x8, *(const int4v*)(xp + ks * 1024));
    }
    #pragma unroll
    for (int k = 0; k < 4; ++k) {
      float e0 = __expf(6.0f * s[4*k+0]);
      float e1 = __expf(6.0f * s[4*k+1]);
      float e2 = __expf(6.0f * s[4*k+2]);
      float e3 = __expf(6.0f * s[4*k+3]);
      csacc += (e0 + e1) + (e2 + e3);
      int base = mloc * 33 + 16 * a_sub + 4 * k + 2 * g;
      Ps[0][base]     = (uint32_t)f2bf(e0) | ((uint32_t)f2bf(e1) << 16);
      Ps[0][base + 1] = (uint32_t)f2bf(e2) | ((uint32_t)f2bf(e3) << 16);
    }
  }
  barrier_lgkm_only();

  // ---- main pipelined loop: bodies t = 0..30 do PV(t) + S(t+1) ----
  for (int t = 0; t < 31; ++t) {
    const int cur = t & 1;
    const int jn  = j0 + t + 1;
    const uint32_t* Pr = Ps[cur];
    uint32_t*       Pw = Ps[cur ^ 1];

    // Af(t+1) batch 0 (ks 0..7)
    bf16x8 Af[16];
    const char* ap = apb + (size_t)(jn * 2) * 16384;
    #pragma unroll
    for (int ks = 0; ks < 8; ++ks)
      Af[ks] = __builtin_bit_cast(bf16x8, *(const int4v*)(ap + ks * 1024));

    f32x16 s;
    #pragma unroll
    for (int r = 0; r < 16; ++r) s[r] = 0.0f;

    // PV(t) groups interleaved with S(t+1) groups (one behind)
    #pragma unroll
    for (int ks = 0; ks < 4; ++ks) {
      if (ks == 2) {  // Af batch 1 (ks 8..15)
        #pragma unroll
        for (int k2 = 8; k2 < 16; ++k2)
          Af[k2] = __builtin_bit_cast(bf16x8, *(const int4v*)(ap + k2 * 1024));
      }
      bf16x8 Bp[2];
      #pragma unroll
      for (int mm = 0; mm < 2; ++mm) {
        int b = (32 * mm + l31) * 33 + (2 * ks + g) * 4;
        union { uint32_t u[4]; bf16x8 v; } tb;
        tb.u[0] = Pr[b];     tb.u[1] = Pr[b + 1];
        tb.u[2] = Pr[b + 2]; tb.u[3] = Pr[b + 3];
        Bp[mm] = tb.v;
      }
      #pragma unroll
      for (int t2 = 0; t2 < 2; ++t2) {
        accO[t2][0] = __builtin_amdgcn_mfma_f32_32x32x16_bf16(Xf[t2][ks], Bp[0], accO[t2][0], 0,0,0);
        accO[t2][1] = __builtin_amdgcn_mfma_f32_32x32x16_bf16(Xf[t2][ks], Bp[1], accO[t2][1], 0,0,0);
      }
      if (ks > 0) {  // S group ks-1: Af[4(ks-1) .. 4ks-1]
        #pragma unroll
        for (int i = 0; i < 4; ++i)
          s = __builtin_amdgcn_mfma_f32_32x32x16_bf16(Af[4*(ks-1)+i], Bm[4*(ks-1)+i], s, 0, 0, 0);
      }
    }

    // Xf(t+1): issued after last PV use of Xf(t); covered by S tail + exp
    #pragma unroll
    for (int t2 = 0; t2 < 2; ++t2) {
      const char* xp = xpb + (size_t)(2 * w + t2) * 524288 + (size_t)(jn * 8) * 512;
      #pragma unroll
      for (int ks = 0; ks < 4; ++ks)
        Xf[t2][ks] = __builtin_bit_cast(bf16x8, *(const int4v*)(xp + ks * 1024));
    }

    // S tail group (Af[12..15])
    #pragma unroll
    for (int i = 12; i < 16; ++i)
      s = __builtin_amdgcn_mfma_f32_32x32x16_bf16(Af[i], Bm[i], s, 0, 0, 0);

    // exp/pack(t+1) -> other Ps buffer
    #pragma unroll
    for (int k = 0; k < 4; ++k) {
      float e0 = __expf(6.0f * s[4*k+0]);
      float e1 = __expf(6.0f * s[4*k+1]);
      float e2 = __expf(6.0f * s[4*k+2]);
      float e3 = __expf(6.0f * s[4*k+3]);
      csacc += (e0 + e1) + (e2 + e3);
      int base = mloc * 33 + 16 * a_sub + 4 * k + 2 * g;
      Pw[base]     = (uint32_t)f2bf(e0) | ((uint32_t)f2bf(e1) << 16);
      Pw[base + 1] = (uint32_t)f2bf(e2) | ((uint32_t)f2bf(e3) << 16);
    }
    barrier_lgkm_only();
  }

  // ---- epilogue body: PV(31) only ----
  {
    const uint32_t* Pr = Ps[31 & 1];
    #pragma unroll
    for (int ks = 0; ks < 4; ++ks) {
      bf16x8 Bp[2];
      #pragma unroll
      for (int mm = 0; mm < 2; ++mm) {
        int b = (32 * mm + l31) * 33 + (2 * ks + g) * 4;
        union { uint32_t u[4]; bf16x8 v; } tb;
        tb.u[0] = Pr[b];     tb.u[1] = Pr[b + 1];
        tb.u[2] = Pr[b + 2]; tb.u[3] = Pr[b + 3];
        Bp[mm] = tb.v;
      }
      #pragma unroll
      for (int t2 = 0; t2 < 2; ++t2) {
        accO[t2][0] = __builtin_amdgcn_mfma_f32_32x32x16_bf16(Xf[t2][ks], Bp[0], accO[t2][0], 0,0,0);
        accO[t2][1] = __builtin_amdgcn_mfma_f32_32x32x16_bf16(Xf[t2][ks], Bp[1], accO[t2][1], 0,0,0);
      }
    }
  }

  // ---- merge partials ----
  csacc += __shfl_xor(csacc, 32, 64);
  if (g == 0) atomicAdd(&cs[m0 + mloc], csacc);
  #pragma unroll
  for (int t2 = 0; t2 < 2; ++t2)
    #pragma unroll
    for (int mm = 0; mm < 2; ++mm)
      #pragma unroll
      for (int r = 0; r < 16; ++r) {
        int drow = 32 * (2 * w + t2) + (r & 3) + 8 * (r >> 2) + 4 * g;
        int mg   = m0 + 32 * mm + l31;
        atomicAdd(&num[(size_t)drow * NPTS + mg], accO[t2][mm][r]);
      }
}

// ---------------------------------------------------------------------------
// Combine. mode1: v = num/cs -> yout. mode0: v = src (initial X).
// Both: emit xaf + xbf frags; zero numz after read; zero csz (next iter's cs).
// ---------------------------------------------------------------------------
__global__ __launch_bounds__(256) void ms_combine(
    const float* __restrict__ src, const float* __restrict__ csr,
    float* __restrict__ csz, float* __restrict__ yout,
    float* __restrict__ numz,
    uint16_t* __restrict__ xaf, uint16_t* __restrict__ xbf,
    const int mode)
{
  __shared__ uint16_t T[64][66];
  const int tid = threadIdx.x;
  const int n0 = blockIdx.x * 64;
  const int d0 = blockIdx.y * 64;

  #pragma unroll
  for (int i = 0; i < 4; ++i) {
    int e  = tid + i * 256;              // float4 slot
    int dl = e >> 4, nq = e & 15;
    size_t idx = (size_t)(d0 + dl) * NPTS + (n0 + nq * 4);
    f32x4 v = *(const f32x4*)(src + idx);
    if (mode) {
      f32x4 c = *(const f32x4*)(csr + n0 + nq * 4);
      v /= c;
      *(f32x4*)(yout + idx) = v;
    }
    f32x4 z = {0.f, 0.f, 0.f, 0.f};
    *(f32x4*)(numz + idx) = z;           // zero num for next fused dispatch
    #pragma unroll
    for (int k = 0; k < 4; ++k) T[dl][nq * 4 + k] = f2bf(v[k]);
  }
  if (blockIdx.y == 0 && tid < 64) csz[n0 + tid] = 0.0f;
  __syncthreads();

  char* xafc = (char*)xaf;
  char* xbfc = (char*)xbf;
  // xaf chunks: (nb, s, lane) -> T[s*8 + j][nb*32+lane]
  #pragma unroll
  for (int i = 0; i < 2; ++i) {
    int c  = tid + i * 256;
    int nb = c >> 8, s2 = (c >> 5) & 7, ln = c & 31;
    union { uint32_t u[4]; int4v v; } pk;
    #pragma unroll
    for (int k = 0; k < 4; ++k) {
      uint32_t lo = T[s2 * 8 + 2 * k][nb * 32 + ln];
      uint32_t hi = T[s2 * 8 + 2 * k + 1][nb * 32 + ln];
      pk.u[k] = lo | (hi << 16);
    }
    *(int4v*)(xafc + (size_t)(n0 / 32 + nb) * 16384 +
              (size_t)(d0 / 8 + s2) * 512 + ln * 16) = pk.v;
  }
  // xbf chunks: (db, u, lane) -> T[db*32+lane][u*8 + j]
  #pragma unroll
  for (int i = 0; i < 2; ++i) {
    int c  = tid + i * 256;
    int db = c >> 8, uu = (c >> 5) & 7, ln = c & 31;
    const uint16_t* tr = &T[db * 32 + ln][uu * 8];
    union { uint32_t u[4]; int4v v; } pk;
    #pragma unroll
    for (int k = 0; k < 4; ++k)
      pk.u[k] = (uint32_t)tr[2 * k] | ((uint32_t)tr[2 * k + 1] << 16);
    *(int4v*)(xbfc + (size_t)(d0 / 32 + db) * 524288 +
              (size_t)(n0 / 8 + uu) * 512 + ln * 16) = pk.v;
  }
}

extern "C" void kernel_launch(void* const* d_in, const int* in_sizes, int n_in,
                              void* d_out, int out_size, void* d_ws, size_t ws_size,
                              hipStream_t stream)
{
  (void)in_sizes; (void)n_in; (void)out_size; (void)ws_size;
  const float* X = (const float*)d_in[0];
  float* out = (float*)d_out;
  char* ws = (char*)d_ws;
  // ws: [0,4M) xaf ; [4M,8M) xbf ; [8M,16M) num ; [16M,+32K) cs0 ; [+32K) cs1
  uint16_t* xaf = (uint16_t*)(ws);
  uint16_t* xbf = (uint16_t*)(ws + (4u << 20));
  float*    num = (float*)   (ws + (8u << 20));
  float*    cs0 = (float*)   (ws + (16u << 20));
  float*    cs1 = (float*)   (ws + (16u << 20) + 32768);

  dim3 cgrid(NPTS / 64, DFEAT / 64);
  // mode0 zeroes num + cs0 (no memset dispatch needed)
  ms_combine<<<cgrid, 256, 0, stream>>>(X, nullptr, cs0, nullptr, num,
                                        xaf, xbf, 0);
  for (int it = 0; it < 3; ++it) {
    float* csA = (it & 1) ? cs1 : cs0;
    float* csB = (it & 1) ? cs0 : cs1;
    ms_fused<<<512, 256, 0, stream>>>(xaf, xbf, num, csA);
    ms_combine<<<cgrid, 256, 0, stream>>>(num, csA, csB,
                                          out + (size_t)it * DFEAT * NPTS,
                                          num, xaf, xbf, 1);
  }
}

// Round 8
// 367.867 us; speedup vs baseline: 1.0744x; 1.0744x over previous
//
#include <hip/hip_runtime.h>
#include <hip/hip_bf16.h>
#include <stdint.h>

#define DFEAT 256
#define NPTS  8192

typedef __attribute__((ext_vector_type(8)))  short bf16x8;   // 8 bf16 = 4 VGPRs
typedef __attribute__((ext_vector_type(16))) float f32x16;   // 32x32 C/D
typedef __attribute__((ext_vector_type(4)))  int   int4v;
typedef __attribute__((ext_vector_type(4)))  float f32x4;

#define AS1 __attribute__((address_space(1)))
#define AS3 __attribute__((address_space(3)))

__device__ inline void dma16(const void* g, void* l) {
  // async global->LDS, 16B/lane; LDS dest = wave-uniform base + lane*16
  __builtin_amdgcn_global_load_lds((const AS1 uint32_t*)g, (AS3 uint32_t*)l, 16, 0, 0);
}

__device__ inline uint16_t f2bf(float f) {  // RNE fp32->bf16
  union { float f; uint32_t u; } v; v.f = f;
  return (uint16_t)((v.u + 0x7FFFu + ((v.u >> 16) & 1u)) >> 16);
}

// lgkmcnt(0)-only barrier: Ps visibility without draining the in-flight DMA.
__device__ inline void barrier_lgkm_only() {
  __asm__ __volatile__("" ::: "memory");
  __builtin_amdgcn_s_waitcnt(0xC07F);   // vmcnt=63, expcnt=7, lgkmcnt=0
  __builtin_amdgcn_s_barrier();
  __asm__ __volatile__("" ::: "memory");
}

// ---------------------------------------------------------------------------
// ws fragment layouts (written by ms_combine):
//  xaf: per 32-point block nb, chunk s=2*ks+g, lane 0..31:
//       X[d = s*8 .. +8][pt = nb*32+lane]  (A/B-frag order, k=d)  (4 MB)
//  xbf: per 32-d block db, chunk u (n/8), lane:
//       X[d = db*32+lane][n = u*8 .. +8]   (PV A-frag order, k=n) (4 MB)
// ---------------------------------------------------------------------------

// m-tile 128, 512-thread WG (8 waves), 1 WG/CU (LDS-forced), grid 256.
// Per iter (n-tile 64): 256 MFMA vs 64 KB L2 traffic (2x intensity of the
// 64-tile version). S: wave=(n_sub=w&1, m_sub=w>>1), Bm resident, Af from
// DMA-staged LDS (identity copy). PV: wave=d-block w, all 4 m-subs; Xf = 4
// global loads/wave (no duplication); Bp from Ps (odd-stride, conflict-free).
__global__ __launch_bounds__(512, 2) void ms_fused(
    const uint16_t* __restrict__ xaf,
    const uint16_t* __restrict__ xbf,
    float* __restrict__ num,           // [256][8192] fp32, zeroed by combine
    float* __restrict__ cs)            // [8192] fp32, zeroed by combine
{
  __shared__ __attribute__((aligned(16))) uint16_t XS[2][16384]; // 2x32KB stage
  __shared__ uint32_t Ps[128 * 33];                              // 16896 B

  const int tid  = threadIdx.x;
  const int w    = tid >> 6;                 // 0..7
  const int lane = tid & 63;
  const int l31  = lane & 31;
  const int g    = lane >> 5;
  const int bid  = blockIdx.x;
  const int xcd  = bid & 7;                  // blockIdx%8 ~ XCD (heuristic)
  const int q    = xcd >> 1;                 // n-split shared per XCD (L2-hot)
  const int mt   = (bid >> 3) + ((xcd & 1) << 5);   // 0..63
  const int m0   = mt * 128;
  const int n_sub = w & 1;                   // S: n half (0/1)
  const int m_sub = w >> 1;                  // S: m quarter (0..3)

  const char* xafc = (const char*)xaf;
  const char* xbfc = (const char*)xbf;

  // Bm resident: 16 chunks of the wave's m-sub (64 VGPRs)
  bf16x8 Bm[16];
  {
    const char* bp = xafc + (size_t)(m0 / 32 + m_sub) * 16384 + g * 512 + l31 * 16;
    #pragma unroll
    for (int ks = 0; ks < 16; ++ks)
      Bm[ks] = __builtin_bit_cast(bf16x8, *(const int4v*)(bp + ks * 1024));
  }

  f32x16 accO[4];                            // PV: d-block w, m-subs 0..3
  #pragma unroll
  for (int m = 0; m < 4; ++m)
    #pragma unroll
    for (int r = 0; r < 16; ++r) accO[m][r] = 0.0f;
  float csacc = 0.0f;

  const int mrow = 32 * m_sub + l31;         // S output column (m)
  const int j0   = q * 32;

  // prologue: DMA tile j0 -> XS[0] (identity copy, 4x16B per thread)
  {
    const char* src = xafc + (size_t)j0 * 32768;
    #pragma unroll
    for (int r = 0; r < 4; ++r)
      dma16(src + r * 8192 + tid * 16, (char*)XS[0] + r * 8192 + tid * 16);
  }

  for (int t = 0; t < 32; ++t) {
    const int jt  = j0 + t;
    const int cur = t & 1;
    __syncthreads();  // A: DMA(t) landed in XS[cur]; PV(t-1) Ps reads done

    // Xf(t): 4 coalesced global loads (issued first; latency covered by S)
    bf16x8 Xf[4];
    {
      const char* xp = xbfc + (size_t)w * 524288 + (size_t)(jt * 8 + g) * 512 + l31 * 16;
      #pragma unroll
      for (int ks = 0; ks < 4; ++ks)
        Xf[ks] = __builtin_bit_cast(bf16x8, *(const int4v*)(xp + ks * 1024));
    }
    __asm__ __volatile__("" ::: "memory");

    // DMA(t+1) -> other stage buffer (drained at next barrier A)
    if (t < 31) {
      const char* src = xafc + (size_t)(jt + 1) * 32768;
      #pragma unroll
      for (int r = 0; r < 4; ++r)
        dma16(src + r * 8192 + tid * 16,
              (char*)XS[cur ^ 1] + r * 8192 + tid * 16);
    }

    // ---- S = Xn^T Xm (32n x 32m quadrant), dual chains ----
    f32x16 s0, s1;
    #pragma unroll
    for (int r = 0; r < 16; ++r) { s0[r] = 0.0f; s1[r] = 0.0f; }
    {
      const char* ap = (const char*)XS[cur] + n_sub * 16384 + g * 512 + l31 * 16;
      #pragma unroll
      for (int ks2 = 0; ks2 < 8; ++ks2) {
        bf16x8 A0 = __builtin_bit_cast(bf16x8, *(const int4v*)(ap + (2*ks2) * 1024));
        bf16x8 A1 = __builtin_bit_cast(bf16x8, *(const int4v*)(ap + (2*ks2+1) * 1024));
        s0 = __builtin_amdgcn_mfma_f32_32x32x16_bf16(A0, Bm[2*ks2],   s0, 0, 0, 0);
        s1 = __builtin_amdgcn_mfma_f32_32x32x16_bf16(A1, Bm[2*ks2+1], s1, 0, 0, 0);
      }
    }

    // ---- P = exp(6S); colsum; pack to Ps (8 b32, conflict-free) ----
    #pragma unroll
    for (int k = 0; k < 4; ++k) {
      float e0 = __expf(6.0f * (s0[4*k+0] + s1[4*k+0]));
      float e1 = __expf(6.0f * (s0[4*k+1] + s1[4*k+1]));
      float e2 = __expf(6.0f * (s0[4*k+2] + s1[4*k+2]));
      float e3 = __expf(6.0f * (s0[4*k+3] + s1[4*k+3]));
      csacc += (e0 + e1) + (e2 + e3);
      int base = mrow * 33 + 16 * n_sub + 4 * k + 2 * g;
      Ps[base]     = (uint32_t)f2bf(e0) | ((uint32_t)f2bf(e1) << 16);
      Ps[base + 1] = (uint32_t)f2bf(e2) | ((uint32_t)f2bf(e3) << 16);
    }
    barrier_lgkm_only();  // B: Ps visible; DMA(t+1) keeps flying

    // ---- O[d-block w][all m] += Xn * P : 4 independent chains ----
    #pragma unroll
    for (int ks = 0; ks < 4; ++ks) {
      bf16x8 Bp[4];
      #pragma unroll
      for (int m = 0; m < 4; ++m) {
        int b = (32 * m + l31) * 33 + 8 * ks + 4 * g;
        union { uint32_t u[4]; bf16x8 v; } tb;
        tb.u[0] = Ps[b];     tb.u[1] = Ps[b + 1];
        tb.u[2] = Ps[b + 2]; tb.u[3] = Ps[b + 3];
        Bp[m] = tb.v;
      }
      #pragma unroll
      for (int m = 0; m < 4; ++m)
        accO[m] = __builtin_amdgcn_mfma_f32_32x32x16_bf16(Xf[ks], Bp[m], accO[m], 0,0,0);
    }
  }

  // ---- merge partials ----
  csacc += __shfl_xor(csacc, 32, 64);
  if (g == 0) atomicAdd(&cs[m0 + mrow], csacc);
  #pragma unroll
  for (int m = 0; m < 4; ++m)
    #pragma unroll
    for (int r = 0; r < 16; ++r) {
      int drow = 32 * w + (r & 3) + 8 * (r >> 2) + 4 * g;
      int mg   = m0 + 32 * m + l31;
      atomicAdd(&num[(size_t)drow * NPTS + mg], accO[m][r]);
    }
}

// ---------------------------------------------------------------------------
// Combine. mode0: v = src (initial X); emit frags; zero num+cs.
//          mode1: v = num/cs -> yout; emit frags; zero num+cs.
//          mode2: v = num/cs -> yout only (last iteration).
// ---------------------------------------------------------------------------
__global__ __launch_bounds__(256) void ms_combine(
    const float* __restrict__ src, const float* __restrict__ csr,
    float* __restrict__ csz, float* __restrict__ yout,
    float* __restrict__ numz,
    uint16_t* __restrict__ xaf, uint16_t* __restrict__ xbf,
    const int mode)
{
  __shared__ uint16_t T[64][66];
  const int tid = threadIdx.x;
  const int n0 = blockIdx.x * 64;
  const int d0 = blockIdx.y * 64;
  const bool divide = (mode >= 1);
  const bool emit   = (mode <= 1);

  #pragma unroll
  for (int i = 0; i < 4; ++i) {
    int e  = tid + i * 256;              // float4 slot
    int dl = e >> 4, nq = e & 15;
    size_t idx = (size_t)(d0 + dl) * NPTS + (n0 + nq * 4);
    f32x4 v = *(const f32x4*)(src + idx);
    if (divide) {
      f32x4 c = *(const f32x4*)(csr + n0 + nq * 4);
      v /= c;
      *(f32x4*)(yout + idx) = v;
    }
    if (emit) {
      f32x4 z = {0.f, 0.f, 0.f, 0.f};
      *(f32x4*)(numz + idx) = z;         // zero num for next fused dispatch
      #pragma unroll
      for (int k = 0; k < 4; ++k) T[dl][nq * 4 + k] = f2bf(v[k]);
    }
  }
  if (!emit) return;
  if (blockIdx.y == 0 && tid < 64) csz[n0 + tid] = 0.0f;
  __syncthreads();

  char* xafc = (char*)xaf;
  char* xbfc = (char*)xbf;
  // xaf chunks: (nb, s, lane) -> T[s*8 + j][nb*32+lane]
  #pragma unroll
  for (int i = 0; i < 2; ++i) {
    int c  = tid + i * 256;
    int nb = c >> 8, s2 = (c >> 5) & 7, ln = c & 31;
    union { uint32_t u[4]; int4v v; } pk;
    #pragma unroll
    for (int k = 0; k < 4; ++k) {
      uint32_t lo = T[s2 * 8 + 2 * k][nb * 32 + ln];
      uint32_t hi = T[s2 * 8 + 2 * k + 1][nb * 32 + ln];
      pk.u[k] = lo | (hi << 16);
    }
    *(int4v*)(xafc + (size_t)(n0 / 32 + nb) * 16384 +
              (size_t)(d0 / 8 + s2) * 512 + ln * 16) = pk.v;
  }
  // xbf chunks: (db, u, lane) -> T[db*32+lane][u*8 + j]
  #pragma unroll
  for (int i = 0; i < 2; ++i) {
    int c  = tid + i * 256;
    int db = c >> 8, uu = (c >> 5) & 7, ln = c & 31;
    const uint16_t* tr = &T[db * 32 + ln][uu * 8];
    union { uint32_t u[4]; int4v v; } pk;
    #pragma unroll
    for (int k = 0; k < 4; ++k)
      pk.u[k] = (uint32_t)tr[2 * k] | ((uint32_t)tr[2 * k + 1] << 16);
    *(int4v*)(xbfc + (size_t)(d0 / 32 + db) * 524288 +
              (size_t)(n0 / 8 + uu) * 512 + ln * 16) = pk.v;
  }
}

extern "C" void kernel_launch(void* const* d_in, const int* in_sizes, int n_in,
                              void* d_out, int out_size, void* d_ws, size_t ws_size,
                              hipStream_t stream)
{
  (void)in_sizes; (void)n_in; (void)out_size; (void)ws_size;
  const float* X = (const float*)d_in[0];
  float* out = (float*)d_out;
  char* ws = (char*)d_ws;
  // ws: [0,4M) xaf ; [4M,8M) xbf ; [8M,16M) num ; [16M,+32K) cs0 ; [+32K) cs1
  uint16_t* xaf = (uint16_t*)(ws);
  uint16_t* xbf = (uint16_t*)(ws + (4u << 20));
  float*    num = (float*)   (ws + (8u << 20));
  float*    cs0 = (float*)   (ws + (16u << 20));
  float*    cs1 = (float*)   (ws + (16u << 20) + 32768);

  dim3 cgrid(NPTS / 64, DFEAT / 64);
  // mode0 zeroes num + cs0 (no memset dispatch needed)
  ms_combine<<<cgrid, 256, 0, stream>>>(X, nullptr, cs0, nullptr, num,
                                        xaf, xbf, 0);
  for (int it = 0; it < 3; ++it) {
    float* csA = (it & 1) ? cs1 : cs0;
    float* csB = (it & 1) ? cs0 : cs1;
    ms_fused<<<256, 512, 0, stream>>>(xaf, xbf, num, csA);
    ms_combine<<<cgrid, 256, 0, stream>>>(num, csA, csB,
                                          out + (size_t)it * DFEAT * NPTS,
                                          num, xaf, xbf, (it == 2) ? 2 : 1);
  }
}